// Round 11
// baseline (157.324 us; speedup 1.0000x reference)
//
#include <hip/hip_runtime.h>

// Problem constants (fixed by the reference's setup_inputs)
#define NB 2          // batch
#define NN 262144     // events per batch (2^18)
#define ND 10         // temporal bins (base)
#define NR 11         // warp references (base + 1)
#define HH 256
#define WW 256
#define HWSZ 65536
#define SROWS 8       // rows per y-strip
#define NSTRIP 32     // 256 / SROWS
#define PLANE (SROWS * WW)        // 2048 pixels per strip plane
#define BINS_B (NR * NSTRIP)      // 352 bins per batch
#define NBIN (NB * BINS_B)        // 704 bins total
#define BINCAP (2u * NB * NN * NR)  // 11,534,336 worst-case entries
#define NBLK 512                  // prep/fill shared block decomposition
#define BPB 256                   // blocks per batch (NBLK / NB)
#define EPSF 1e-9f

// fixed-point scales for packed u64 (iwe | iwt) LDS accumulation (order-indep):
#define SC_E 2097152.0f
#define SC_T 524288.0f
#define ISC_E (1.0f / 2097152.0f)
#define ISC_T (1.0f / 524288.0f)

// R11 theory (from R10 counters): R10's -33% bins bytes bought only -4.6us ->
// scan is LDS-ATOMIC-floor-bound (~21M u64 lane-RMW @ ~1/cyc/CU ~= 37us; R7's
// 6x15us for the same atomic count confirms the rate), and fill was bound by
// its 3-phase structure (2 classify passes, stash round-trip, cursor atomics),
// not bytes. This round restructures the support around the atomic floor:
//   * prep writes per-block hist PLAIN (no global atomics) -> hist_g[512][352]
//   * prefix builds starts[704] AND per-(block,bin) local bases lb[512][352]
//     -> fill is SINGLE-PASS (classify -> rank -> pack -> write); no stash,
//        no count pass (-5.9M LDS atomics), no cursor atomics
//   * dispatches 6 -> 4: memset gone (prefix zeroes accum+ctr), final fused
//     into scan's last-arriving block (threadfence + arrival counter)
// Entry format (u64) and scan inner loop unchanged from R10.

__device__ __forceinline__ unsigned classify(float ax, float ay, float dx, float dy, float rf)
{
    // 0xFF if no corner can land; else strip | (straddle ? 0x40 : 0)
    float wx = fmaf(rf, dx, ax);
    float wy = fmaf(rf, dy, ay);
    int xi = (int)floorf(wx);
    int yi = (int)floorf(wy);
    if (xi + 1 < 0 || xi >= WW || yi + 1 < 0 || yi >= HH) return 0xFFu;
    int rr = yi < 0 ? 0 : yi;
    unsigned s = (unsigned)(rr >> 3);                 // SROWS = 8
    unsigned str = (yi >= 0 && yi + 1 < HH && ((yi & 7) == 7)) ? 0x40u : 0u;
    return s | str;
}

__global__ __launch_bounds__(1024) void cm_prep(
    const float* __restrict__ events,
    const float* __restrict__ flow,
    float4* __restrict__ rec,
    float* __restrict__ tspol,
    unsigned* __restrict__ hist_g)
{
    __shared__ unsigned hist[BINS_B];           // 352 counters, 1.4 KB
    for (int i = threadIdx.x; i < BINS_B; i += 1024) hist[i] = 0u;
    __syncthreads();

    int gid = blockIdx.x * 1024 + threadIdx.x;  // NBLK=512 blocks cover NB*NN
    int b = gid >> 18;                          // uniform per block

    const float* e = events + (size_t)gid * 5;
    float x  = e[0];
    float y  = e[1];
    float t  = e[2];
    float ts = e[3];
    float p  = e[4];

    int zi = (int)floorf(t);
    zi = zi < 0 ? 0 : (zi > ND - 1 ? ND - 1 : zi);
    int x0 = (int)floorf(x);
    x0 = x0 < 0 ? 0 : (x0 > WW - 2 ? WW - 2 : x0);
    int y0 = (int)floorf(y);
    y0 = y0 < 0 ? 0 : (y0 > HH - 2 ? HH - 2 : y0);
    float fx = fminf(fmaxf(x - (float)x0, 0.0f), 1.0f);
    float fy = fminf(fmaxf(y - (float)y0, 0.0f), 1.0f);

    const float2* f2 = (const float2*)flow + ((size_t)b * ND + zi) * HWSZ;
    float2 f00 = f2[y0 * WW + x0];
    float2 f01 = f2[y0 * WW + x0 + 1];
    float2 f10 = f2[(y0 + 1) * WW + x0];
    float2 f11 = f2[(y0 + 1) * WW + x0 + 1];
    float w00 = (1.0f - fx) * (1.0f - fy);
    float w01 = fx * (1.0f - fy);
    float w10 = (1.0f - fx) * fy;
    float w11 = fx * fy;
    float dx = w00 * f00.x + w01 * f01.x + w10 * f10.x + w11 * f11.x;
    float dy = w00 * f00.y + w01 * f01.y + w10 * f10.y + w11 * f11.y;
    float ax = fmaf(-t, dx, x);
    float ay = fmaf(-t, dy, y);

    rec[gid] = make_float4(ax, ay, dx, dy);
    int pi = (p != 0.0f) ? 1 : 0;
    tspol[gid] = __int_as_float(__float_as_int(ts) | (pi << 31));   // ts >= 0

    #pragma unroll
    for (int r = 0; r < NR; ++r) {
        unsigned c = classify(ax, ay, dx, dy, (float)r);
        if (c != 0xFFu) {
            int bin = r * NSTRIP + (int)(c & 31u);
            atomicAdd(&hist[bin], 1u);
            if (c & 0x40u) atomicAdd(&hist[bin + 1], 1u);   // straddle dup
        }
    }
    __syncthreads();
    // plain coalesced store -- no global atomics
    for (int i = threadIdx.x; i < BINS_B; i += 1024)
        hist_g[(size_t)blockIdx.x * BINS_B + i] = hist[i];
}

// builds starts[NBIN(+1)], per-(block,bin) local bases lb[NBLK][BINS_B],
// and zeroes accum + arrival counter (replaces memset + enables fused final)
__global__ __launch_bounds__(1024) void cm_prefix(
    const unsigned* __restrict__ hist_g,
    unsigned* __restrict__ lb,
    unsigned* __restrict__ starts,
    float* __restrict__ accum,
    unsigned* __restrict__ ctr)
{
    __shared__ unsigned sa[1024];
    int tid = threadIdx.x;

    unsigned v = 0;
    if (tid < NBIN) {
        int batch = tid / BINS_B;
        int bl = tid - batch * BINS_B;
        const unsigned* hcol = hist_g + (size_t)batch * BPB * BINS_B + bl;
        unsigned* lcol = lb + (size_t)batch * BPB * BINS_B + bl;
        unsigned running = 0;
        #pragma unroll 4
        for (int g = 0; g < BPB; ++g) {             // coalesced across lanes
            lcol[(size_t)g * BINS_B] = running;
            running += hcol[(size_t)g * BINS_B];
        }
        v = running;                                 // bin total
    }
    sa[tid] = v;
    __syncthreads();
    for (int off = 1; off < 1024; off <<= 1) {
        unsigned x = sa[tid];
        if (tid >= off) x += sa[tid - off];
        __syncthreads();
        sa[tid] = x;
        __syncthreads();
    }
    if (tid < NBIN) {
        starts[tid] = tid ? sa[tid - 1] : 0u;
    }
    if (tid == 0) starts[NBIN] = sa[NBIN - 1];
    if (tid < 64) accum[tid] = 0.0f;
    if (tid == 64) *ctr = 0u;
}

__global__ __launch_bounds__(1024) void cm_fill(
    const float4* __restrict__ rec,
    const float* __restrict__ tspol,
    const unsigned* __restrict__ lb,
    const unsigned* __restrict__ starts,
    unsigned long long* __restrict__ bins)
{
    __shared__ unsigned base_l[BINS_B];           // starts + this block's lb row
    __shared__ unsigned cnt[BINS_B];              // rank counters

    int gid = blockIdx.x * 1024 + threadIdx.x;    // NBLK=512 blocks, 1 event/thread
    int b = gid >> 18;                            // uniform per block

    for (int i = threadIdx.x; i < BINS_B; i += 1024) {
        base_l[i] = starts[b * BINS_B + i] + lb[(size_t)blockIdx.x * BINS_B + i];
        cnt[i] = 0u;
    }
    __syncthreads();

    float4 ea = rec[gid];
    float tpv = tspol[gid];
    unsigned pol = (unsigned)__float_as_int(tpv) >> 31;
    float tsv = fabsf(tpv);
    unsigned et = __float2uint_rn(tsv * 65536.0f);            // 20 bits
    unsigned long long hdr = ((unsigned long long)et << 43) |
                             ((unsigned long long)pol << 63);

    // single pass: classify -> rank -> pack -> write (no stash, no count phase)
    #pragma unroll
    for (int r = 0; r < NR; ++r) {
        unsigned c = classify(ea.x, ea.y, ea.z, ea.w, (float)r);
        if (c != 0xFFu) {
            float rf = (float)r;
            float wx = fmaf(rf, ea.z, ea.x);   // bit-identical chain
            float wy = fmaf(rf, ea.w, ea.y);
            int sid = (int)(c & 31u);
            float ty0f = (float)(sid * SROWS);
            unsigned ex = __float2uint_rn((wx + 1.0f) * 32768.0f);        // 24b
            unsigned ey = __float2uint_rn((wy - ty0f + 1.0f) * 32768.0f); // 19b
            unsigned long long ent = hdr | (unsigned long long)ex |
                                     ((unsigned long long)ey << 24);
            int bin = r * NSTRIP + sid;
            unsigned rank = atomicAdd(&cnt[bin], 1u);
            bins[base_l[bin] + rank] = ent;
            if (c & 0x40u) {                          // straddle dup into s+1
                unsigned ey2 = __float2uint_rn((wy - ty0f - (float)SROWS + 1.0f) * 32768.0f);
                unsigned long long ent2 = hdr | (unsigned long long)ex |
                                          ((unsigned long long)ey2 << 24);
                unsigned rank2 = atomicAdd(&cnt[bin + 1], 1u);
                bins[base_l[bin + 1] + rank2] = ent2;
            }
        }
    }
}

__global__ __launch_bounds__(1024) void cm_scan(
    const unsigned long long* __restrict__ bins,
    const unsigned* __restrict__ starts,
    float* __restrict__ accum,
    unsigned* __restrict__ ctr,
    float* __restrict__ out)
{
    __shared__ unsigned long long acc8[2 * PLANE];   // 32 KB: [pol][px] packed (iwe|iwt)
    __shared__ float red[32];                        // wave partials / last-block flag

    int blk = blockIdx.x;                            // 0 .. NBIN-1
    int b  = blk / BINS_B;
    int rm = blk - b * BINS_B;
    int r  = rm >> 5;

    for (int i = threadIdx.x; i < 2 * PLANE; i += 1024) acc8[i] = 0ull;
    __syncthreads();

    unsigned lo = starts[blk];
    unsigned hi = starts[blk + 1];

    auto process = [&](unsigned long long e) {
        float wx  = (float)(unsigned)(e & 0xFFFFFFu) * (1.0f / 32768.0f) - 1.0f;
        float wyr = (float)(unsigned)((e >> 24) & 0x7FFFFu) * (1.0f / 32768.0f) - 1.0f;
        float tsv = (float)(unsigned)((e >> 43) & 0xFFFFFu) * (1.0f / 65536.0f);
        int pi = (int)(e >> 63);
        float fwx = floorf(wx);
        float fwy = floorf(wyr);
        int xi = (int)fwx;
        int yi = (int)fwy;                           // strip-relative: -1..9
        float axf = wx - fwx;
        float ayf = wyr - fwy;
        unsigned long long* ap = acc8 + pi * PLANE;
        float c00 = (1.0f - axf) * (1.0f - ayf);
        float c01 = axf * (1.0f - ayf);
        float c10 = (1.0f - axf) * ayf;
        float c11 = axf * ayf;
        #define CM_CORNER(XI, YI, WV)                                          \
            if ((XI) >= 0 && (XI) < WW && (YI) >= 0 && (YI) < SROWS) {         \
                int liq = (YI) * WW + (XI);                                    \
                unsigned pe = __float2uint_rn((WV) * SC_E);                    \
                unsigned pt = __float2uint_rn((WV) * tsv * SC_T);              \
                atomicAdd(&ap[liq],                                            \
                          ((unsigned long long)pt << 32) | (unsigned long long)pe); \
            }
        CM_CORNER(xi,     yi,     c00)
        CM_CORNER(xi + 1, yi,     c01)
        CM_CORNER(xi,     yi + 1, c10)
        CM_CORNER(xi + 1, yi + 1, c11)
        #undef CM_CORNER
    };

    // head-align to even entry index so uint4 loads are 16B-aligned
    unsigned lo2 = lo + (lo & 1u);
    if ((lo & 1u) && threadIdx.x == 0 && lo < hi) process(bins[lo]);

    const uint4* bv = (const uint4*)bins;
    for (unsigned bse = lo2 + 4u * threadIdx.x; bse < hi; bse += 4096u) {
        uint4 A = bv[bse >> 1];                 // entries bse, bse+1
        uint4 B = bv[(bse >> 1) + 1];           // entries bse+2, bse+3 (alloc slack ok)
        __builtin_amdgcn_sched_barrier(0);      // pin both wide loads ahead of use
        unsigned long long e0 = (unsigned long long)A.x | ((unsigned long long)A.y << 32);
        unsigned long long e1 = (unsigned long long)A.z | ((unsigned long long)A.w << 32);
        unsigned long long e2 = (unsigned long long)B.x | ((unsigned long long)B.y << 32);
        unsigned long long e3 = (unsigned long long)B.z | ((unsigned long long)B.w << 32);
        process(e0);
        if (bse + 1 < hi) process(e1);
        if (bse + 2 < hi) process(e2);
        if (bse + 3 < hi) process(e3);
    }
    __syncthreads();

    float ss = 0.0f, ins = 0.0f;
    for (int i = threadIdx.x; i < PLANE; i += 1024) {   // 2 iters (PLANE=2048)
        unsigned long long v0 = acc8[i];
        unsigned long long v1 = acc8[PLANE + i];
        unsigned e0i = (unsigned)(v0 & 0xFFFFFFFFull);
        unsigned e1i = (unsigned)(v1 & 0xFFFFFFFFull);
        float e0 = (float)e0i * ISC_E;
        float t0 = (float)(unsigned)(v0 >> 32) * ISC_T;
        float e1 = (float)e1i * ISC_E;
        float t1 = (float)(unsigned)(v1 >> 32) * ISC_T;
        float a0 = t0 / (e0 + EPSF);
        float a1 = t1 / (e1 + EPSF);
        ss += a0 * a0 + a1 * a1;
        ins += ((e0i | e1i) != 0u) ? 1.0f : 0.0f;
    }
    #pragma unroll
    for (int off = 32; off > 0; off >>= 1) {
        ss  += __shfl_down(ss, off, 64);
        ins += __shfl_down(ins, off, 64);
    }
    int lane = threadIdx.x & 63;
    int wv = threadIdx.x >> 6;                      // 0..15
    if (lane == 0) { red[2 * wv] = ss; red[2 * wv + 1] = ins; }
    __syncthreads();
    if (threadIdx.x == 0) {
        float tss = 0.0f, tin = 0.0f;
        #pragma unroll
        for (int w = 0; w < 16; ++w) { tss += red[2 * w]; tin += red[2 * w + 1]; }
        int br = b * NR + r;
        atomicAdd(&accum[br * 2],     tss);
        atomicAdd(&accum[br * 2 + 1], tin);
        __threadfence();
        unsigned old = atomicAdd(ctr, 1u);
        red[0] = (old == NBIN - 1) ? 1.0f : 0.0f;   // am I the last block?
    }
    __syncthreads();
    if (red[0] != 0.0f && threadIdx.x < NB * NR) {
        // fused cm_final: atomic read-back dodges stale L1 after cross-CU adds
        float num = atomicAdd(&accum[threadIdx.x * 2],     0.0f);
        float den = atomicAdd(&accum[threadIdx.x * 2 + 1], 0.0f);
        out[threadIdx.x] = num / (den + EPSF);
    }
}

extern "C" void kernel_launch(void* const* d_in, const int* in_sizes, int n_in,
                              void* d_out, int out_size, void* d_ws, size_t ws_size,
                              hipStream_t stream) {
    const float* events = (const float*)d_in[0];
    const float* flow   = (const float*)d_in[1];

    char* ws = (char*)d_ws;
    size_t off = 0;
    unsigned long long* bins = (unsigned long long*)(ws + off);
    off += (size_t)BINCAP * 8;                                                 // 92,274,688
    float4* rec = (float4*)(ws + off);         off += (size_t)NB * NN * sizeof(float4); // 8,388,608
    float* tspol = (float*)(ws + off);         off += (size_t)NB * NN * sizeof(float);  // 2,097,152
    unsigned* hist_g = (unsigned*)(ws + off);  off += (size_t)NBLK * BINS_B * 4;        // 720,896
    unsigned* lb = (unsigned*)(ws + off);      off += (size_t)NBLK * BINS_B * 4;        // 720,896
    unsigned* starts = (unsigned*)(ws + off);  off += (NBIN + 1) * 4 + 60; off &= ~63ull;
    float* accum = (float*)(ws + off);         off += 64 * 4;
    unsigned* ctr = (unsigned*)(ws + off);     off += 64;
    // total ~104.5 MB of the 256 MiB workspace; 4 dispatches, no memset

    cm_prep<<<NBLK, 1024, 0, stream>>>(events, flow, rec, tspol, hist_g);

    cm_prefix<<<1, 1024, 0, stream>>>(hist_g, lb, starts, accum, ctr);

    cm_fill<<<NBLK, 1024, 0, stream>>>(rec, tspol, lb, starts, bins);

    cm_scan<<<NBIN, 1024, 0, stream>>>(bins, starts, accum, ctr, (float*)d_out);
}

// Round 12
// 143.242 us; speedup vs baseline: 1.0983x; 1.0983x over previous
//
#include <hip/hip_runtime.h>

// Problem constants (fixed by the reference's setup_inputs)
#define NB 2          // batch
#define NN 262144     // events per batch (2^18)
#define ND 10         // temporal bins (base)
#define NR 11         // warp references (base + 1)
#define HH 256
#define WW 256
#define HWSZ 65536
#define SROWS 8       // rows per y-strip
#define NSTRIP 32     // 256 / SROWS
#define PLANE (SROWS * WW)        // 2048 pixels per strip plane
#define BINS_B (NR * NSTRIP)      // 352 bins per batch
#define NBIN (NB * BINS_B)        // 704 scan blocks
#define FB_E 1024                 // events per build block
#define NFB (NB * NN / FB_E)      // 512 build blocks
#define FBPB (NN / FB_E)          // 256 build blocks per batch
#define MAXPB (FB_E * 2 * NR)     // 22528 worst-case entries per build block
#define DSTR 356                  // dir row stride (353 used)
#define EPSF 1e-9f

// fixed-point scales for packed u64 (iwe | iwt) LDS accumulation (order-indep):
#define SC_E 2097152.0f
#define SC_T 524288.0f
#define ISC_E (1.0f / 2097152.0f)
#define ISC_T (1.0f / 524288.0f)

// R12 theory (from R11 regression): R11's global compaction support (serial
// 256-iter prefix column walk + halved fill chunks) cost more than it saved;
// scan remains DS-atomic-floor-bound (~37us) and fill scatter-write-bound.
// Fix: drop global compaction entirely. cm_build fuses prep+fill -- warp
// computed straight from events+flow (no rec/tspol 21MB round-trip), per-block
// LDS count -> in-LDS exclusive scan -> chunk DIRECTORY row dir[block][bin] ->
// entries written to the block's OWN bins region (block-local contiguous
// chunks, no global atomics, no prefix kernel, no memset). cm_scan walks its
// bin's 256 chunks via the directory (wave-per-chunk, coalesced u64 reads);
// inner splat loop + u64 packed LDS accumulation + fused final unchanged from
// the R10/R11-verified code. 2 dispatches total. Entry format (u64):
//   bits 0-23: (wx+1)*2^15 | 24-42: (wy-ty0+1)*2^15 | 43-62: ts*2^16 | 63: pol

__device__ __forceinline__ unsigned classify(float ax, float ay, float dx, float dy, float rf)
{
    // 0xFF if no corner can land; else strip | (straddle ? 0x40 : 0)
    float wx = fmaf(rf, dx, ax);
    float wy = fmaf(rf, dy, ay);
    int xi = (int)floorf(wx);
    int yi = (int)floorf(wy);
    if (xi + 1 < 0 || xi >= WW || yi + 1 < 0 || yi >= HH) return 0xFFu;
    int rr = yi < 0 ? 0 : yi;
    unsigned s = (unsigned)(rr >> 3);                 // SROWS = 8
    unsigned str = (yi >= 0 && yi + 1 < HH && ((yi & 7) == 7)) ? 0x40u : 0u;
    return s | str;
}

__global__ __launch_bounds__(1024) void cm_build(
    const float* __restrict__ events,
    const float* __restrict__ flow,
    unsigned long long* __restrict__ bins,
    unsigned* __restrict__ dir,
    float* __restrict__ accum,
    unsigned* __restrict__ ctr)
{
    __shared__ unsigned char stash[FB_E * NR];    // 11.0 KB classify cache
    __shared__ unsigned cnt[BINS_B];              // counts, then rank counters
    __shared__ unsigned ofs[BINS_B + 1];          // exclusive scan result
    __shared__ unsigned sa[1024];                 // scan workspace

    if (blockIdx.x == 0) {                        // replaces memset (idempotent per launch)
        if (threadIdx.x < 64) accum[threadIdx.x] = 0.0f;
        if (threadIdx.x == 64) *ctr = 0u;
    }
    for (int i = threadIdx.x; i < BINS_B; i += 1024) cnt[i] = 0u;
    __syncthreads();

    int gid = blockIdx.x * FB_E + threadIdx.x;    // 512 blocks cover NB*NN
    int b = gid >> 18;                            // uniform per block

    // ---- warp computation straight from inputs (chain identical to R10/R11) ----
    const float* e = events + (size_t)gid * 5;
    float x  = e[0];
    float y  = e[1];
    float t  = e[2];
    float ts = e[3];
    float p  = e[4];

    int zi = (int)floorf(t);
    zi = zi < 0 ? 0 : (zi > ND - 1 ? ND - 1 : zi);
    int x0 = (int)floorf(x);
    x0 = x0 < 0 ? 0 : (x0 > WW - 2 ? WW - 2 : x0);
    int y0 = (int)floorf(y);
    y0 = y0 < 0 ? 0 : (y0 > HH - 2 ? HH - 2 : y0);
    float fx = fminf(fmaxf(x - (float)x0, 0.0f), 1.0f);
    float fy = fminf(fmaxf(y - (float)y0, 0.0f), 1.0f);

    const float2* f2 = (const float2*)flow + ((size_t)b * ND + zi) * HWSZ;
    float2 f00 = f2[y0 * WW + x0];
    float2 f01 = f2[y0 * WW + x0 + 1];
    float2 f10 = f2[(y0 + 1) * WW + x0];
    float2 f11 = f2[(y0 + 1) * WW + x0 + 1];
    float w00 = (1.0f - fx) * (1.0f - fy);
    float w01 = fx * (1.0f - fy);
    float w10 = (1.0f - fx) * fy;
    float w11 = fx * fy;
    float dx = w00 * f00.x + w01 * f01.x + w10 * f10.x + w11 * f11.x;
    float dy = w00 * f00.y + w01 * f01.y + w10 * f10.y + w11 * f11.y;
    float ax = fmaf(-t, dx, x);
    float ay = fmaf(-t, dy, y);

    unsigned pol = (p != 0.0f) ? 1u : 0u;
    unsigned et = __float2uint_rn(ts * 65536.0f);             // 20 bits (ts < 10)
    unsigned long long hdr = ((unsigned long long)et << 43) |
                             ((unsigned long long)pol << 63);

    // ---- phase A: classify + LDS count ----
    #pragma unroll
    for (int r = 0; r < NR; ++r) {
        unsigned c = classify(ax, ay, dx, dy, (float)r);
        stash[threadIdx.x * NR + r] = (unsigned char)c;
        if (c != 0xFFu) {
            int bin = r * NSTRIP + (int)(c & 31u);
            atomicAdd(&cnt[bin], 1u);
            if (c & 0x40u) atomicAdd(&cnt[bin + 1], 1u);   // straddle dup
        }
    }
    __syncthreads();

    // ---- phase B: in-LDS exclusive scan (352 -> ofs), write dir row ----
    sa[threadIdx.x] = (threadIdx.x < BINS_B) ? cnt[threadIdx.x] : 0u;
    __syncthreads();
    for (int off = 1; off < 512; off <<= 1) {     // 352 <= 512
        unsigned v = sa[threadIdx.x];
        if (threadIdx.x >= off) v += sa[threadIdx.x - off];
        __syncthreads();
        sa[threadIdx.x] = v;
        __syncthreads();
    }
    if (threadIdx.x < BINS_B) ofs[threadIdx.x] = threadIdx.x ? sa[threadIdx.x - 1] : 0u;
    if (threadIdx.x == 0) ofs[BINS_B] = sa[BINS_B - 1];
    __syncthreads();
    for (int i = threadIdx.x; i < BINS_B; i += 1024) cnt[i] = 0u;   // reuse as ranks
    for (int i = threadIdx.x; i <= BINS_B; i += 1024)               // chunk directory
        dir[(size_t)blockIdx.x * DSTR + i] = ofs[i];
    __syncthreads();

    // ---- phase C: pack + write entries to this block's OWN region ----
    unsigned long long* reg = bins + (size_t)blockIdx.x * MAXPB;
    #pragma unroll
    for (int r = 0; r < NR; ++r) {
        unsigned c = stash[threadIdx.x * NR + r];
        if (c != 0xFFu) {
            float rf = (float)r;
            float wx = fmaf(rf, dx, ax);
            float wy = fmaf(rf, dy, ay);
            int sid = (int)(c & 31u);
            float ty0f = (float)(sid * SROWS);
            unsigned exq = __float2uint_rn((wx + 1.0f) * 32768.0f);        // 24b
            unsigned eyq = __float2uint_rn((wy - ty0f + 1.0f) * 32768.0f); // 19b
            unsigned long long ent = hdr | (unsigned long long)exq |
                                     ((unsigned long long)eyq << 24);
            int bin = r * NSTRIP + sid;
            unsigned rank = atomicAdd(&cnt[bin], 1u);
            reg[ofs[bin] + rank] = ent;
            if (c & 0x40u) {                          // straddle dup into s+1
                unsigned eyq2 = __float2uint_rn((wy - ty0f - (float)SROWS + 1.0f) * 32768.0f);
                unsigned long long ent2 = hdr | (unsigned long long)exq |
                                          ((unsigned long long)eyq2 << 24);
                unsigned rank2 = atomicAdd(&cnt[bin + 1], 1u);
                reg[ofs[bin + 1] + rank2] = ent2;
            }
        }
    }
}

__global__ __launch_bounds__(512) void cm_scan(
    const unsigned long long* __restrict__ bins,
    const unsigned* __restrict__ dir,
    float* __restrict__ accum,
    unsigned* __restrict__ ctr,
    float* __restrict__ out)
{
    __shared__ unsigned long long acc8[2 * PLANE];   // 32 KB: [pol][px] packed (iwe|iwt)
    __shared__ float red[16];                        // 8 wave partials / last flag

    int blk = blockIdx.x;                            // 0 .. NBIN-1
    int b  = blk / BINS_B;
    int bl = blk - b * BINS_B;                       // bin within batch
    int r  = bl >> 5;

    for (int i = threadIdx.x; i < 2 * PLANE; i += 512) acc8[i] = 0ull;
    __syncthreads();

    int lane = threadIdx.x & 63;
    int wv   = threadIdx.x >> 6;                     // 0..7

    auto process = [&](unsigned long long e) {
        float wx  = (float)(unsigned)(e & 0xFFFFFFu) * (1.0f / 32768.0f) - 1.0f;
        float wyr = (float)(unsigned)((e >> 24) & 0x7FFFFu) * (1.0f / 32768.0f) - 1.0f;
        float tsv = (float)(unsigned)((e >> 43) & 0xFFFFFu) * (1.0f / 65536.0f);
        int pi = (int)(e >> 63);
        float fwx = floorf(wx);
        float fwy = floorf(wyr);
        int xi = (int)fwx;
        int yi = (int)fwy;                           // strip-relative: -1..8
        float axf = wx - fwx;
        float ayf = wyr - fwy;
        unsigned long long* ap = acc8 + pi * PLANE;
        float c00 = (1.0f - axf) * (1.0f - ayf);
        float c01 = axf * (1.0f - ayf);
        float c10 = (1.0f - axf) * ayf;
        float c11 = axf * ayf;
        #define CM_CORNER(XI, YI, WV)                                          \
            if ((XI) >= 0 && (XI) < WW && (YI) >= 0 && (YI) < SROWS) {         \
                int liq = (YI) * WW + (XI);                                    \
                unsigned pe = __float2uint_rn((WV) * SC_E);                    \
                unsigned pt = __float2uint_rn((WV) * tsv * SC_T);              \
                atomicAdd(&ap[liq],                                            \
                          ((unsigned long long)pt << 32) | (unsigned long long)pe); \
            }
        CM_CORNER(xi,     yi,     c00)
        CM_CORNER(xi + 1, yi,     c01)
        CM_CORNER(xi,     yi + 1, c10)
        CM_CORNER(xi + 1, yi + 1, c11)
        #undef CM_CORNER
    };

    // wave-per-chunk walk of this bin's 256 chunks (one per build block)
    for (int g = b * FBPB + wv; g < (b + 1) * FBPB; g += 8) {
        unsigned s = dir[(size_t)g * DSTR + bl];
        unsigned e = dir[(size_t)g * DSTR + bl + 1];
        const unsigned long long* reg = bins + (size_t)g * MAXPB;
        for (unsigned i = s + (unsigned)lane; i < e; i += 64u)
            process(reg[i]);
    }
    __syncthreads();

    float ss = 0.0f, ins = 0.0f;
    for (int i = threadIdx.x; i < PLANE; i += 512) {   // 4 iters (PLANE=2048)
        unsigned long long v0 = acc8[i];
        unsigned long long v1 = acc8[PLANE + i];
        unsigned e0i = (unsigned)(v0 & 0xFFFFFFFFull);
        unsigned e1i = (unsigned)(v1 & 0xFFFFFFFFull);
        float e0 = (float)e0i * ISC_E;
        float t0 = (float)(unsigned)(v0 >> 32) * ISC_T;
        float e1 = (float)e1i * ISC_E;
        float t1 = (float)(unsigned)(v1 >> 32) * ISC_T;
        float a0 = t0 / (e0 + EPSF);
        float a1 = t1 / (e1 + EPSF);
        ss += a0 * a0 + a1 * a1;
        ins += ((e0i | e1i) != 0u) ? 1.0f : 0.0f;
    }
    #pragma unroll
    for (int off = 32; off > 0; off >>= 1) {
        ss  += __shfl_down(ss, off, 64);
        ins += __shfl_down(ins, off, 64);
    }
    if (lane == 0) { red[2 * wv] = ss; red[2 * wv + 1] = ins; }
    __syncthreads();
    if (threadIdx.x == 0) {
        float tss = 0.0f, tin = 0.0f;
        #pragma unroll
        for (int w = 0; w < 8; ++w) { tss += red[2 * w]; tin += red[2 * w + 1]; }
        int br = b * NR + r;
        atomicAdd(&accum[br * 2],     tss);
        atomicAdd(&accum[br * 2 + 1], tin);
        __threadfence();
        unsigned old = atomicAdd(ctr, 1u);
        red[0] = (old == NBIN - 1) ? 1.0f : 0.0f;   // am I the last block?
    }
    __syncthreads();
    if (red[0] != 0.0f && threadIdx.x < NB * NR) {
        // fused cm_final: atomic read-back dodges stale L1 after cross-CU adds
        float num = atomicAdd(&accum[threadIdx.x * 2],     0.0f);
        float den = atomicAdd(&accum[threadIdx.x * 2 + 1], 0.0f);
        out[threadIdx.x] = num / (den + EPSF);
    }
}

extern "C" void kernel_launch(void* const* d_in, const int* in_sizes, int n_in,
                              void* d_out, int out_size, void* d_ws, size_t ws_size,
                              hipStream_t stream) {
    const float* events = (const float*)d_in[0];
    const float* flow   = (const float*)d_in[1];

    char* ws = (char*)d_ws;
    size_t off = 0;
    unsigned long long* bins = (unsigned long long*)(ws + off);
    off += (size_t)NFB * MAXPB * 8;                              // 92,274,688
    unsigned* dir = (unsigned*)(ws + off);
    off += (size_t)NFB * DSTR * 4;                               // 729,088
    float* accum = (float*)(ws + off);  off += 64 * 4;
    unsigned* ctr = (unsigned*)(ws + off); off += 64;
    // total ~93 MB of the 256 MiB workspace; 2 dispatches, no memset

    cm_build<<<NFB, 1024, 0, stream>>>(events, flow, bins, dir, accum, ctr);

    cm_scan<<<NBIN, 512, 0, stream>>>(bins, dir, accum, ctr, (float*)d_out);
}